// Round 20
// baseline (92.426 us; speedup 1.0000x reference)
//
#include <hip/hip_runtime.h>

#define BATCH 4096
#define DIM   512
#define NROW  8192
#define TILE  128
#define NCH   64                      // 128-row/col chunks
#define NBLK  (NCH * (NCH + 1) / 2)   // 2080 triangle cells (incl. diagonal)
#define NSLOT 64
#define NSTEP 4                       // K-steps of 128 fp8 bytes

typedef __attribute__((ext_vector_type(4))) float f32x4;
typedef __attribute__((ext_vector_type(8))) int   i32x8;

// ---- f32 -> fp8 e4m3fn RNE (|x|<=1 here; proven r11/r12/r17/r18) ----
__device__ inline unsigned f2fp8(float f) {
    unsigned u = __float_as_uint(f);
    unsigned s = (u >> 31) << 7;
    unsigned mag = u & 0x7fffffffu;
    unsigned q = (mag + 0x7FFFFu + ((mag >> 20) & 1u)) >> 20;
    int e8 = (int)(q >> 3) - 120;
    if (e8 >= 1) return s | ((unsigned)e8 << 3) | (q & 7u);
    float t = __uint_as_float(mag) * 512.0f;
    return s | (unsigned)rintf(t);
}

__device__ __forceinline__ void gload16(const unsigned char* g, unsigned char* l) {
    __builtin_amdgcn_global_load_lds(
        (const __attribute__((address_space(1))) void*)g,
        (__attribute__((address_space(3))) void*)l, 16, 0, 0);
}

// ---------------- Kernel 1: normalize rows + positives -> fp8 reps ----------
// PLAIN k-linear fp8 layout (MX path reads 32 contiguous K-bytes per lane).
__global__ __launch_bounds__(256) void normalize_pos_kernel(
    const float* __restrict__ ei, const float* __restrict__ ej,
    unsigned char* __restrict__ reps, float* __restrict__ pos) {
    const int t = threadIdx.x & 63;
    const int i = blockIdx.x * 4 + (threadIdx.x >> 6);

    const float4* ri = (const float4*)(ei + (size_t)i * DIM);
    const float4* rj = (const float4*)(ej + (size_t)i * DIM);
    float4 a0 = ri[t], a1 = ri[t + 64];
    float4 b0 = rj[t], b1 = rj[t + 64];

    float si  = a0.x*a0.x + a0.y*a0.y + a0.z*a0.z + a0.w*a0.w
              + a1.x*a1.x + a1.y*a1.y + a1.z*a1.z + a1.w*a1.w;
    float sj  = b0.x*b0.x + b0.y*b0.y + b0.z*b0.z + b0.w*b0.w
              + b1.x*b1.x + b1.y*b1.y + b1.z*b1.z + b1.w*b1.w;
    float dij = a0.x*b0.x + a0.y*b0.y + a0.z*b0.z + a0.w*b0.w
              + a1.x*b1.x + a1.y*b1.y + a1.z*b1.z + a1.w*b1.w;

    #pragma unroll
    for (int m = 1; m < 64; m <<= 1) {
        si  += __shfl_xor(si,  m);
        sj  += __shfl_xor(sj,  m);
        dij += __shfl_xor(dij, m);
    }
    float invi = 1.0f / fmaxf(sqrtf(si), 1e-12f);
    float invj = 1.0f / fmaxf(sqrtf(sj), 1e-12f);

    unsigned wa0 = f2fp8(a0.x*invi) | (f2fp8(a0.y*invi) << 8)
                 | (f2fp8(a0.z*invi) << 16) | (f2fp8(a0.w*invi) << 24);
    unsigned wa1 = f2fp8(a1.x*invi) | (f2fp8(a1.y*invi) << 8)
                 | (f2fp8(a1.z*invi) << 16) | (f2fp8(a1.w*invi) << 24);
    unsigned wb0 = f2fp8(b0.x*invj) | (f2fp8(b0.y*invj) << 8)
                 | (f2fp8(b0.z*invj) << 16) | (f2fp8(b0.w*invj) << 24);
    unsigned wb1 = f2fp8(b1.x*invj) | (f2fp8(b1.y*invj) << 8)
                 | (f2fp8(b1.z*invj) << 16) | (f2fp8(b1.w*invj) << 24);

    unsigned char* wi = reps + (size_t)i * DIM;
    unsigned char* wj = reps + (size_t)(BATCH + i) * DIM;
    *(unsigned*)(wi + 4 * t)       = wa0;
    *(unsigned*)(wi + 256 + 4 * t) = wa1;
    *(unsigned*)(wj + 4 * t)       = wb0;
    *(unsigned*)(wj + 256 + 4 * t) = wb1;
    if (t == 0) pos[i] = dij * invi * invj;
}

// ---------------- Kernel 2: triangle 128x128 cells, MX-fp8 K=128 -----------
// r18's winning structure (4 waves, 64x64/wave, single LDS buffer, plain
// 2-__syncthreads loop, high occupancy) with mfma_scale 16x16x128 (unit
// scales): half the MFMA pipe time at the same LDS bytes. 128-B LDS rows
// with XOR-slot swizzle (physical slot = logical ^ (row&7)), applied on
// the gload SOURCE (linear dest, rule 21) and the ds_read address.
__global__ __launch_bounds__(256) void simsum_kernel(
    const unsigned char* __restrict__ reps, float* __restrict__ partials) {
    __shared__ unsigned char lds[32768];   // A [128][128B] | B [128][128B]

    int bid = (blockIdx.x & 7) * (NBLK / 8) + (blockIdx.x >> 3);  // 2080 = 8*260
    int rc = 0, b = bid;
    while (b >= NCH - rc) { b -= NCH - rc; ++rc; }
    const int cc = rc + b;                    // rc <= cc
    const bool isDiag = (rc == cc);

    const int tid  = threadIdx.x;
    const int lane = tid & 63;
    const int wave = tid >> 6;                // 0..3
    const int wr = wave >> 1, wc = wave & 1;
    const int s = lane & 15, q = lane >> 4;
    const int rr = lane >> 3;                 // staging row-in-8 (0..7)
    const int slot = lane & 7;                // staging 16B slot
    const int rowBase = rc * TILE, colBase = cc * TILE;

    // staging source: per-lane row + XOR-swizzled slot (linear LDS dest)
    const unsigned char* gArow = reps + (size_t)(rowBase + wave * 32 + rr) * DIM
                               + ((slot ^ rr) << 4);
    const unsigned char* gBrow = reps + (size_t)(colBase + wave * 32 + rr) * DIM
                               + ((slot ^ rr) << 4);

    // ds_read swizzled byte offsets: row&7 == s&7 for rows wr*64+m*16+s
    const int arow = (wr * 64 + s) * 128;            // + m*2048
    const int brow = 16384 + (wc * 64 + s) * 128;    // + n*2048
    const int sw0 = (((q * 2)     ^ (s & 7)) << 4);  // logical chunk q*2
    const int sw1 = (((q * 2 + 1) ^ (s & 7)) << 4);  // logical chunk q*2+1

    f32x4 acc[4][4];
    #pragma unroll
    for (int m = 0; m < 4; ++m)
        #pragma unroll
        for (int n = 0; n < 4; ++n) acc[m][n] = (f32x4){0.f,0.f,0.f,0.f};

    for (int t = 0; t < NSTEP; ++t) {
        __syncthreads();                       // prev readers done
        const int kb = t * 128;
        #pragma unroll
        for (int i = 0; i < 4; ++i) {
            gload16(gArow + i * 4096 + kb, lds + (wave * 32 + i * 8) * 128);
            gload16(gBrow + i * 4096 + kb, lds + 16384 + (wave * 32 + i * 8) * 128);
        }
        __syncthreads();                       // publish (compiler drains vmcnt)

        i32x8 a8[4], b8[4];
        #pragma unroll
        for (int m = 0; m < 4; ++m) {
            int4 lo = *(const int4*)((const char*)lds + arow + m * 2048 + sw0);
            int4 hi = *(const int4*)((const char*)lds + arow + m * 2048 + sw1);
            a8[m] = (i32x8){lo.x, lo.y, lo.z, lo.w, hi.x, hi.y, hi.z, hi.w};
        }
        #pragma unroll
        for (int n = 0; n < 4; ++n) {
            int4 lo = *(const int4*)((const char*)lds + brow + n * 2048 + sw0);
            int4 hi = *(const int4*)((const char*)lds + brow + n * 2048 + sw1);
            b8[n] = (i32x8){lo.x, lo.y, lo.z, lo.w, hi.x, hi.y, hi.z, hi.w};
        }

        // 16 MX MFMAs (K=128 each, fp8 fmt=0, unit scales E8M0=127 -> 1.0)
        #pragma unroll
        for (int m = 0; m < 4; ++m)
            #pragma unroll
            for (int n = 0; n < 4; ++n)
                acc[m][n] = __builtin_amdgcn_mfma_scale_f32_16x16x128_f8f6f4(
                    a8[m], b8[n], acc[m][n], 0, 0, 0, 127, 0, 127);
    }

    // ---- epilogue: exp(sim/T); diag masked; row + col sums (r18-verified) ----
    const float SCALE = 2.8853900817779268f;   // 1/(TEMP*ln2) = 2/ln2
    float* red = (float*)lds;                  // [2][128] rowsum | [2][128] colsum
    __syncthreads();
    float colacc[4] = {0.f,0.f,0.f,0.f};
    #pragma unroll
    for (int m = 0; m < 4; ++m) {
        const int lrow0 = wr * 64 + m * 16 + (q << 2);
        const int grow0 = rowBase + lrow0;
        float rs[4] = {0.f,0.f,0.f,0.f};
        #pragma unroll
        for (int n = 0; n < 4; ++n) {
            const int gcol = colBase + wc * 64 + n * 16 + s;
            #pragma unroll
            for (int j = 0; j < 4; ++j) {
                float e = exp2f(acc[m][n][j] * SCALE);
                if (isDiag && (grow0 + j == gcol)) e = 0.f;
                rs[j] += e;
                colacc[n] += e;
            }
        }
        #pragma unroll
        for (int j = 0; j < 4; ++j) {
            float v = rs[j];
            v += __shfl_xor(v, 1); v += __shfl_xor(v, 2);
            v += __shfl_xor(v, 4); v += __shfl_xor(v, 8);
            if (s == 0) red[wc * 128 + lrow0 + j] = v;
        }
    }
    #pragma unroll
    for (int n = 0; n < 4; ++n) {
        float v = colacc[n];
        v += __shfl_xor(v, 16); v += __shfl_xor(v, 32);
        if (q == 0) red[256 + wr * 128 + wc * 64 + n * 16 + s] = v;
    }
    __syncthreads();
    if (tid < TILE) {
        partials[(size_t)cc * NROW + rowBase + tid] = red[tid] + red[128 + tid];
        if (!isDiag)
            partials[(size_t)rc * NROW + colBase + tid] =
                red[256 + tid] + red[384 + tid];
    }
}

// ---------------- Kernel 3a: per-row loss partial sums ----------------
__global__ __launch_bounds__(256) void rowloss_kernel(
    const float* __restrict__ partials, const float* __restrict__ pos,
    double* __restrict__ blocksum) {
    const int t = threadIdx.x;
    const int r = blockIdx.x * 256 + t;
    float denom = 0.f;
    #pragma unroll 16
    for (int c = 0; c < NSLOT; ++c)
        denom += partials[(size_t)c * NROW + r];
    double v = (double)(logf(denom) - 2.0f * pos[r & (BATCH - 1)]);
    __shared__ double redl[256];
    redl[t] = v;
    __syncthreads();
    for (int off = 128; off > 0; off >>= 1) {
        if (t < off) redl[t] += redl[t + off];
        __syncthreads();
    }
    if (t == 0) blocksum[blockIdx.x] = redl[0];
}

__global__ void final2_kernel(const double* __restrict__ blocksum,
                              float* __restrict__ out) {
    if (threadIdx.x == 0) {
        double ssum = 0.0;
        #pragma unroll
        for (int i = 0; i < NROW / 256; ++i) ssum += blocksum[i];
        out[0] = (float)(ssum / (double)NROW);
    }
}

extern "C" void kernel_launch(void* const* d_in, const int* in_sizes, int n_in,
                              void* d_out, int out_size, void* d_ws, size_t ws_size,
                              hipStream_t stream) {
    const float* ei = (const float*)d_in[0];
    const float* ej = (const float*)d_in[1];
    float* out = (float*)d_out;

    unsigned char* reps = (unsigned char*)d_ws;                         // 4 MB fp8
    float* pos      = (float*)((char*)d_ws + (size_t)NROW * DIM);       // 16 KB
    float* partials = pos + BATCH;                                      // 64*8192*4 = 2 MB
    double* blocksum = (double*)(partials + (size_t)NSLOT * NROW);

    normalize_pos_kernel<<<BATCH / 4, 256, 0, stream>>>(ei, ej, reps, pos);
    simsum_kernel<<<NBLK, 256, 0, stream>>>(reps, partials);
    rowloss_kernel<<<NROW / 256, 256, 0, stream>>>(partials, pos, blocksum);
    final2_kernel<<<1, 64, 0, stream>>>(blocksum, out);
}

// Round 21
// 56.598 us; speedup vs baseline: 1.6330x; 1.6330x over previous
//
#include <hip/hip_runtime.h>

#define BATCH 4096
#define DIM   512
#define NROW  8192
#define TILE  128
#define NCH   64                      // 128-row/col chunks
#define NBLK  (NCH * (NCH + 1) / 2)   // 2080 triangle cells (incl. diagonal)
#define NSLOT 64
#define NSTEP 4                       // barrier-phases of 128 fp8 K-bytes

typedef __attribute__((ext_vector_type(4))) float f32x4;
typedef __attribute__((ext_vector_type(2))) long long2v;

// ---- f32 -> fp8 e4m3fn RNE (|x|<=1 here; proven r11-r18, absmax 0.0) ----
__device__ inline unsigned f2fp8(float f) {
    unsigned u = __float_as_uint(f);
    unsigned s = (u >> 31) << 7;
    unsigned mag = u & 0x7fffffffu;
    unsigned q = (mag + 0x7FFFFu + ((mag >> 20) & 1u)) >> 20;
    int e8 = (int)(q >> 3) - 120;
    if (e8 >= 1) return s | ((unsigned)e8 << 3) | (q & 7u);
    float t = __uint_as_float(mag) * 512.0f;
    return s | (unsigned)rintf(t);
}

__device__ __forceinline__ void gload16(const unsigned char* g, unsigned char* l) {
    __builtin_amdgcn_global_load_lds(
        (const __attribute__((address_space(1))) void*)g,
        (__attribute__((address_space(3))) void*)l, 16, 0, 0);
}

// ---------------- Kernel 1: normalize rows + positives -> fp8 reps ----------
// K-permuted layout per 64-byte block: byte p = qq*16 + h*8 + b holds
// k = b + h*32 + qq*8 -> one b128 LDS read = {k<32 half, k>=32 half}.
__global__ __launch_bounds__(256) void normalize_pos_kernel(
    const float* __restrict__ ei, const float* __restrict__ ej,
    unsigned char* __restrict__ reps, float* __restrict__ pos) {
    const int t = threadIdx.x & 63;
    const int i = blockIdx.x * 4 + (threadIdx.x >> 6);

    const float4* ri = (const float4*)(ei + (size_t)i * DIM);
    const float4* rj = (const float4*)(ej + (size_t)i * DIM);
    float4 a0 = ri[t], a1 = ri[t + 64];
    float4 b0 = rj[t], b1 = rj[t + 64];

    float si  = a0.x*a0.x + a0.y*a0.y + a0.z*a0.z + a0.w*a0.w
              + a1.x*a1.x + a1.y*a1.y + a1.z*a1.z + a1.w*a1.w;
    float sj  = b0.x*b0.x + b0.y*b0.y + b0.z*b0.z + b0.w*b0.w
              + b1.x*b1.x + b1.y*b1.y + b1.z*b1.z + b1.w*b1.w;
    float dij = a0.x*b0.x + a0.y*b0.y + a0.z*b0.z + a0.w*b0.w
              + a1.x*b1.x + a1.y*b1.y + a1.z*b1.z + a1.w*b1.w;

    #pragma unroll
    for (int m = 1; m < 64; m <<= 1) {
        si  += __shfl_xor(si,  m);
        sj  += __shfl_xor(sj,  m);
        dij += __shfl_xor(dij, m);
    }
    float invi = 1.0f / fmaxf(sqrtf(si), 1e-12f);
    float invj = 1.0f / fmaxf(sqrtf(sj), 1e-12f);

    const int off0 = (t >> 4) * 64 + ((t >> 1) & 3) * 16 + ((t >> 3) & 1) * 8 + 4 * (t & 1);

    unsigned wa0 = f2fp8(a0.x*invi) | (f2fp8(a0.y*invi) << 8)
                 | (f2fp8(a0.z*invi) << 16) | (f2fp8(a0.w*invi) << 24);
    unsigned wa1 = f2fp8(a1.x*invi) | (f2fp8(a1.y*invi) << 8)
                 | (f2fp8(a1.z*invi) << 16) | (f2fp8(a1.w*invi) << 24);
    unsigned wb0 = f2fp8(b0.x*invj) | (f2fp8(b0.y*invj) << 8)
                 | (f2fp8(b0.z*invj) << 16) | (f2fp8(b0.w*invj) << 24);
    unsigned wb1 = f2fp8(b1.x*invj) | (f2fp8(b1.y*invj) << 8)
                 | (f2fp8(b1.z*invj) << 16) | (f2fp8(b1.w*invj) << 24);

    unsigned char* wi = reps + (size_t)i * DIM;
    unsigned char* wj = reps + (size_t)(BATCH + i) * DIM;
    *(unsigned*)(wi + off0)       = wa0;
    *(unsigned*)(wi + off0 + 256) = wa1;
    *(unsigned*)(wj + off0)       = wb0;
    *(unsigned*)(wj + off0 + 256) = wb1;
    if (t == 0) pos[i] = dij * invi * invj;
}

// ---------------- Kernel 2: triangle 128x128 cells, fp8, BK=128/barrier ----
// r18's winning structure (4 waves, 64x64/wave, plain 2-__syncthreads loop,
// high occupancy, zero-conflict swizzle, L/H-pass fp8 MFMA) with TWO 64-byte
// K-halves per barrier phase: 8 gloads -> sync -> 16 ds_read -> 64 MFMA.
// Halves the sync count (16 -> 8). LDS 32 KB single buffer -> 5 blocks/CU.
__global__ __launch_bounds__(256) void simsum_kernel(
    const unsigned char* __restrict__ reps, float* __restrict__ partials) {
    __shared__ unsigned char lds[32768];   // half0: A|B at 0/8192; half1: +16384

    int bid = (blockIdx.x & 7) * (NBLK / 8) + (blockIdx.x >> 3);  // 2080 = 8*260
    int rc = 0, b = bid;
    while (b >= NCH - rc) { b -= NCH - rc; ++rc; }
    const int cc = rc + b;                    // rc <= cc
    const bool isDiag = (rc == cc);

    const int tid  = threadIdx.x;
    const int lane = tid & 63;
    const int wave = tid >> 6;                // 0..3
    const int wr = wave >> 1, wc = wave & 1;
    const int s = lane & 15, q = lane >> 4;
    const int rowBase = rc * TILE, colBase = cc * TILE;

    // staging: wave w owns rows [32w, 32w+32); pre-swizzled 16B-slot source
    const int lr = lane >> 2;                                  // row-in-16
    const int gb = (((lane & 3) ^ ((lane >> 2) & 3) ^ (lane >> 4)) & 3) * 16;
    const unsigned char* gAw = reps + (size_t)(rowBase + wave * 32 + lr) * DIM + gb;
    const unsigned char* gBw = reps + (size_t)(colBase + wave * 32 + lr) * DIM + gb;

    // ds_read swizzled byte offsets (64 B rows; r6/r15/r18-verified pattern)
    const int sig  = ((s & 3) ^ (s >> 2)) & 3;
    const int koS  = ((q ^ sig) & 3) << 4;
    const int aoff = (wr * 64 + s) * 64 + koS;                 // + m*1024
    const int boff = 8192 + (wc * 64 + s) * 64 + koS;          // + n*1024

    f32x4 acc[4][4];
    #pragma unroll
    for (int m = 0; m < 4; ++m)
        #pragma unroll
        for (int n = 0; n < 4; ++n) acc[m][n] = (f32x4){0.f,0.f,0.f,0.f};

    for (int t = 0; t < NSTEP; ++t) {
        __syncthreads();                       // prev readers done
        const int kb = t * 128;
        // half 0 (k-bytes kb .. kb+63)
        gload16(gAw + kb,            lds + wave * 2048);
        gload16(gAw + 16 * DIM + kb, lds + wave * 2048 + 1024);
        gload16(gBw + kb,            lds + 8192 + wave * 2048);
        gload16(gBw + 16 * DIM + kb, lds + 8192 + wave * 2048 + 1024);
        // half 1 (k-bytes kb+64 .. kb+127)
        gload16(gAw + kb + 64,            lds + 16384 + wave * 2048);
        gload16(gAw + 16 * DIM + kb + 64, lds + 16384 + wave * 2048 + 1024);
        gload16(gBw + kb + 64,            lds + 24576 + wave * 2048);
        gload16(gBw + 16 * DIM + kb + 64, lds + 24576 + wave * 2048 + 1024);
        __syncthreads();                       // publish (compiler drains vmcnt)

        long2v af[2][4], bf[2][4];
        #pragma unroll
        for (int h = 0; h < 2; ++h) {
            const char* base = (const char*)lds + h * 16384;
            #pragma unroll
            for (int m = 0; m < 4; ++m) af[h][m] = *(const long2v*)(base + aoff + m * 1024);
            #pragma unroll
            for (int n = 0; n < 4; ++n) bf[h][n] = *(const long2v*)(base + boff + n * 1024);
        }

        // per half: L-pass then H-pass (no back-to-back acc dependencies)
        #pragma unroll
        for (int h = 0; h < 2; ++h) {
            #pragma unroll
            for (int m = 0; m < 4; ++m)
                #pragma unroll
                for (int n = 0; n < 4; ++n)
                    acc[m][n] = __builtin_amdgcn_mfma_f32_16x16x32_fp8_fp8(
                        af[h][m][0], bf[h][n][0], acc[m][n], 0, 0, 0);
            #pragma unroll
            for (int m = 0; m < 4; ++m)
                #pragma unroll
                for (int n = 0; n < 4; ++n)
                    acc[m][n] = __builtin_amdgcn_mfma_f32_16x16x32_fp8_fp8(
                        af[h][m][1], bf[h][n][1], acc[m][n], 0, 0, 0);
        }
    }

    // ---- epilogue: exp(sim/T); diag masked; row + col sums (r18-verified) ----
    const float SCALE = 2.8853900817779268f;   // 1/(TEMP*ln2) = 2/ln2
    float* red = (float*)lds;                  // [2][128] rowsum | [2][128] colsum
    __syncthreads();
    float colacc[4] = {0.f,0.f,0.f,0.f};
    #pragma unroll
    for (int m = 0; m < 4; ++m) {
        const int lrow0 = wr * 64 + m * 16 + (q << 2);
        const int grow0 = rowBase + lrow0;
        float rs[4] = {0.f,0.f,0.f,0.f};
        #pragma unroll
        for (int n = 0; n < 4; ++n) {
            const int gcol = colBase + wc * 64 + n * 16 + s;
            #pragma unroll
            for (int j = 0; j < 4; ++j) {
                float e = exp2f(acc[m][n][j] * SCALE);
                if (isDiag && (grow0 + j == gcol)) e = 0.f;
                rs[j] += e;
                colacc[n] += e;
            }
        }
        #pragma unroll
        for (int j = 0; j < 4; ++j) {
            float v = rs[j];
            v += __shfl_xor(v, 1); v += __shfl_xor(v, 2);
            v += __shfl_xor(v, 4); v += __shfl_xor(v, 8);
            if (s == 0) red[wc * 128 + lrow0 + j] = v;
        }
    }
    #pragma unroll
    for (int n = 0; n < 4; ++n) {
        float v = colacc[n];
        v += __shfl_xor(v, 16); v += __shfl_xor(v, 32);
        if (q == 0) red[256 + wr * 128 + wc * 64 + n * 16 + s] = v;
    }
    __syncthreads();
    if (tid < TILE) {
        partials[(size_t)cc * NROW + rowBase + tid] = red[tid] + red[128 + tid];
        if (!isDiag)
            partials[(size_t)rc * NROW + colBase + tid] =
                red[256 + tid] + red[384 + tid];
    }
}

// ---------------- Kernel 3a: per-row loss partial sums ----------------
__global__ __launch_bounds__(256) void rowloss_kernel(
    const float* __restrict__ partials, const float* __restrict__ pos,
    double* __restrict__ blocksum) {
    const int t = threadIdx.x;
    const int r = blockIdx.x * 256 + t;
    float denom = 0.f;
    #pragma unroll 16
    for (int c = 0; c < NSLOT; ++c)
        denom += partials[(size_t)c * NROW + r];
    double v = (double)(logf(denom) - 2.0f * pos[r & (BATCH - 1)]);
    __shared__ double redl[256];
    redl[t] = v;
    __syncthreads();
    for (int off = 128; off > 0; off >>= 1) {
        if (t < off) redl[t] += redl[t + off];
        __syncthreads();
    }
    if (t == 0) blocksum[blockIdx.x] = redl[0];
}

__global__ void final2_kernel(const double* __restrict__ blocksum,
                              float* __restrict__ out) {
    if (threadIdx.x == 0) {
        double ssum = 0.0;
        #pragma unroll
        for (int i = 0; i < NROW / 256; ++i) ssum += blocksum[i];
        out[0] = (float)(ssum / (double)NROW);
    }
}

extern "C" void kernel_launch(void* const* d_in, const int* in_sizes, int n_in,
                              void* d_out, int out_size, void* d_ws, size_t ws_size,
                              hipStream_t stream) {
    const float* ei = (const float*)d_in[0];
    const float* ej = (const float*)d_in[1];
    float* out = (float*)d_out;

    unsigned char* reps = (unsigned char*)d_ws;                         // 4 MB fp8
    float* pos      = (float*)((char*)d_ws + (size_t)NROW * DIM);       // 16 KB
    float* partials = pos + BATCH;                                      // 64*8192*4 = 2 MB
    double* blocksum = (double*)(partials + (size_t)NSLOT * NROW);

    normalize_pos_kernel<<<BATCH / 4, 256, 0, stream>>>(ei, ej, reps, pos);
    simsum_kernel<<<NBLK, 256, 0, stream>>>(reps, partials);
    rowloss_kernel<<<NROW / 256, 256, 0, stream>>>(partials, pos, blocksum);
    final2_kernel<<<1, 64, 0, stream>>>(blocksum, out);
}